// Round 18
// baseline (359.189 us; speedup 1.0000x reference)
//
#include <hip/hip_runtime.h>
#include <math.h>

#define N_TOK 2048
#define NDIM 512
#define HEADS 8
#define TOPK 16
#define QCOLS 4096
#define LSC 4096.0f          // scaled-lo (kQ/k5/W paths only)
#define ILSC (1.0f/4096.0f)

typedef __attribute__((ext_vector_type(8))) _Float16 f16x8;
typedef __attribute__((ext_vector_type(4))) float f32x4;

__device__ __forceinline__ unsigned short f32_to_f16(float f) {
    _Float16 h = (_Float16)f;
    return __builtin_bit_cast(unsigned short, h);
}
__device__ __forceinline__ float f16_to_f32(unsigned short u) {
    return (float)__builtin_bit_cast(_Float16, u);
}
__device__ __forceinline__ void gl_lds16(const void* g, void* l) {
    __builtin_amdgcn_global_load_lds(
        (const __attribute__((address_space(1))) void*)g,
        (__attribute__((address_space(3))) void*)l, 16, 0, 0);
}

// ---------------- kP: splits. x/down -> UNSCALED lo (kF single-acc);
// Wq/keys/upT -> scaled lo (kQ/k5 dual-acc).
__device__ __forceinline__ void split_f4s(const float* __restrict__ src,
                                          unsigned short* __restrict__ dh,
                                          unsigned short* __restrict__ dl,
                                          int i, float lsc) {
    float4 v = reinterpret_cast<const float4*>(src)[i];
    float vv[4] = {v.x, v.y, v.z, v.w};
    ushort4 h, lo;
    unsigned short* hp = &h.x; unsigned short* lp = &lo.x;
    #pragma unroll
    for (int q = 0; q < 4; ++q) {
        unsigned short hh = f32_to_f16(vv[q]);
        hp[q] = hh;
        lp[q] = f32_to_f16((vv[q] - f16_to_f32(hh)) * lsc);
    }
    reinterpret_cast<ushort4*>(dh)[i] = h;
    reinterpret_cast<ushort4*>(dl)[i] = lo;
}

__global__ __launch_bounds__(256) void kP_split(const float* __restrict__ x,
                                                const float* __restrict__ Wq,
                                                const float* __restrict__ keys,
                                                const float* __restrict__ down,
                                                const float* __restrict__ up,
                                                unsigned short* __restrict__ xh,
                                                unsigned short* __restrict__ xl,
                                                unsigned short* __restrict__ Wqh,
                                                unsigned short* __restrict__ Wql,
                                                unsigned short* __restrict__ ksh,
                                                unsigned short* __restrict__ ksl,
                                                unsigned short* __restrict__ Mth,
                                                unsigned short* __restrict__ Mtl,
                                                unsigned short* __restrict__ upTh,
                                                unsigned short* __restrict__ upTl) {
    const int bid = blockIdx.x;
    const int tid = threadIdx.x;
    if (bid < 256) {                     // x: unscaled lo
        #pragma unroll
        for (int t = 0; t < 4; ++t) split_f4s(x, xh, xl, bid * 1024 + t * 256 + tid, 1.0f);
        return;
    }
    if (bid < 768) {                     // Wq: scaled lo
        const int b = bid - 256;
        #pragma unroll
        for (int t = 0; t < 4; ++t) split_f4s(Wq, Wqh, Wql, b * 1024 + t * 256 + tid, LSC);
        return;
    }
    if (bid < 1024) {                    // keys: scaled lo
        const int b = bid - 768;
        #pragma unroll
        for (int t = 0; t < 4; ++t) split_f4s(keys, ksh, ksl, b * 1024 + t * 256 + tid, LSC);
        return;
    }
    if (bid < 1280) {                    // down row e -> Mt row 4096+e (UNSCALED lo)
        const int e = bid - 1024;
        const int d0 = tid * 2;
        float2 v = *reinterpret_cast<const float2*>(&down[(size_t)e * NDIM + d0]);
        ushort2 h, lo;
        unsigned short h0 = f32_to_f16(v.x);
        unsigned short h1 = f32_to_f16(v.y);
        h.x = h0; h.y = h1;
        lo.x = f32_to_f16(v.x - f16_to_f32(h0));
        lo.y = f32_to_f16(v.y - f16_to_f32(h1));
        *reinterpret_cast<ushort2*>(&Mth[(size_t)(QCOLS + e) * NDIM + d0]) = h;
        *reinterpret_cast<ushort2*>(&Mtl[(size_t)(QCOLS + e) * NDIM + d0]) = lo;
        return;
    }
    // upT: scaled lo (k5 path)
    const int b = bid - 1280;
    #pragma unroll
    for (int dd = 0; dd < 8; ++dd) {
        const int d = b * 8 + dd;
        const int e = tid;
        const float v = up[(size_t)e * NDIM + d];
        unsigned short hh = f32_to_f16(v);
        upTh[(size_t)d * 256 + e] = hh;
        upTl[(size_t)d * 256 + e] = f32_to_f16((v - f16_to_f32(hh)) * LSC);
    }
}

// ---------------- kQ: M = Wq_slice @ keys^T (scaled-lo dual-acc), emits Mt with
// UNSCALED lo (kF consumes). grid (16,16).
__global__ __launch_bounds__(256) void kQ_m1(const unsigned short* __restrict__ Wqh,
                                             const unsigned short* __restrict__ Wql,
                                             const unsigned short* __restrict__ ksh,
                                             const unsigned short* __restrict__ ksl,
                                             unsigned short* __restrict__ Mth,
                                             unsigned short* __restrict__ Mtl) {
    __shared__ __align__(16) char lds[36864];   // A 4KB + B 32KB
    const int tid = threadIdx.x;
    const int w = tid >> 6, l = tid & 63;
    const int c0 = blockIdx.x * 32;
    const int ph = blockIdx.y;
    const int p = ph >> 3, h = ph & 7;
    const int off = p * 2048 + h * 256;
    f32x4 acch[2][4] = {};
    f32x4 accl[2][4] = {};

    for (int s = 0; s < 8; ++s) {
        const int kk = s * 32;
        __syncthreads();
        {   // A: 32 rows x 128B = 4KB
            const int q = w * 1024 + l * 16;
            const int r = q >> 7;
            const int bsw = (q & 127) ^ ((r & 7) << 4);
            const unsigned short* src = (bsw < 64)
                ? Wqh + (size_t)(c0 + r) * QCOLS + off + kk + (bsw >> 1)
                : Wql + (size_t)(c0 + r) * QCOLS + off + kk + ((bsw - 64) >> 1);
            gl_lds16(src, lds + w * 1024);
        }
        #pragma unroll
        for (int t = 0; t < 8; ++t) {   // B: 256 rows x 128B = 32KB
            const int q = w * 8192 + t * 1024 + l * 16;
            const int r = q >> 7;
            const int bsw = (q & 127) ^ ((r & 7) << 4);
            const unsigned short* src = (bsw < 64)
                ? ksh + ((size_t)(h * 256 + r) * 2 + p) * 256 + kk + (bsw >> 1)
                : ksl + ((size_t)(h * 256 + r) * 2 + p) * 256 + kk + ((bsw - 64) >> 1);
            gl_lds16(src, lds + 4096 + w * 8192 + t * 1024);
        }
        __syncthreads();
        const int bq = (l >> 4) * 16;
        f16x8 ah[2], al[2];
        #pragma unroll
        for (int mi = 0; mi < 2; ++mi) {
            const int ra = mi * 16 + (l & 15);
            const int swz = (ra & 7) << 4;
            ah[mi] = *(const f16x8*)(lds + ra * 128 + (bq ^ swz));
            al[mi] = *(const f16x8*)(lds + ra * 128 + ((bq + 64) ^ swz));
        }
        __builtin_amdgcn_s_setprio(1);
        #pragma unroll
        for (int nj = 0; nj < 4; ++nj) {
            const int rb = w * 64 + nj * 16 + (l & 15);
            const int swz = (rb & 7) << 4;
            f16x8 bh = *(const f16x8*)(lds + 4096 + rb * 128 + (bq ^ swz));
            f16x8 bl = *(const f16x8*)(lds + 4096 + rb * 128 + ((bq + 64) ^ swz));
            #pragma unroll
            for (int mi = 0; mi < 2; ++mi) {
                acch[mi][nj] = __builtin_amdgcn_mfma_f32_16x16x32_f16(ah[mi], bh, acch[mi][nj], 0, 0, 0);
                accl[mi][nj] = __builtin_amdgcn_mfma_f32_16x16x32_f16(ah[mi], bl, accl[mi][nj], 0, 0, 0);
                accl[mi][nj] = __builtin_amdgcn_mfma_f32_16x16x32_f16(al[mi], bh, accl[mi][nj], 0, 0, 0);
            }
        }
        __builtin_amdgcn_s_setprio(0);
    }
    #pragma unroll
    for (int mi = 0; mi < 2; ++mi)
        #pragma unroll
        for (int nj = 0; nj < 4; ++nj) {
            const int k = w * 64 + nj * 16 + (l & 15);
            const int cb = c0 + mi * 16 + (l >> 4) * 4;
            ushort4 h4, l4;
            unsigned short* hp = &h4.x; unsigned short* lp = &l4.x;
            #pragma unroll
            for (int r = 0; r < 4; ++r) {
                const float v = fmaf(accl[mi][nj][r], ILSC, acch[mi][nj][r]);
                unsigned short hh = f32_to_f16(v);
                hp[r] = hh;
                lp[r] = f32_to_f16(v - f16_to_f32(hh));   // UNSCALED lo for kF
            }
            *reinterpret_cast<ushort4*>(&Mth[(size_t)(off + k) * NDIM + cb]) = h4;
            *reinterpret_cast<ushort4*>(&Mtl[(size_t)(off + k) * NDIM + cb]) = l4;
        }
}

// ---------------- kF: BM=BN=256, BK=32, 512 threads (8 waves, 4x2; 64x128 tiles),
// single acc chain, 64KB LDS single-buffer. Grid 136: XCD k owns row-tile k
// (A panel L2-resident), sweeps 17 col-strips. launch_bounds(512,2) -> 256 VGPR cap.
#define BM 256
#define BN 256
#define BK 32
__global__ __launch_bounds__(512, 2) void kF_gemm(const unsigned short* __restrict__ xh,
                                                  const unsigned short* __restrict__ xl,
                                                  const unsigned short* __restrict__ Mth,
                                                  const unsigned short* __restrict__ Mtl,
                                                  float* __restrict__ T,
                                                  float* __restrict__ D) {
    __shared__ __align__(16) char lds[65536];   // A 32KB + B 32KB
    const int tid = threadIdx.x;
    const int w = tid >> 6, l = tid & 63;
    const int wr = w >> 1, wc = w & 1;          // 4x2 wave grid: 64-row x 128-col tiles
    const int orig = blockIdx.x;                // 0..135
    const int swz = (orig & 7) * 17 + (orig >> 3);  // bijective (136 = 8*17)
    const int rt = swz / 17;                    // row-tile 0..7 (== XCD id)
    const int by = swz % 17;                    // col strip 0..16
    const int row0 = rt * BM;
    const int colbase = by * 256;
    f32x4 acc[4][8] = {};

    for (int s = 0; s < 16; ++s) {
        const int kk = s * BK;
        __syncthreads();
        #pragma unroll
        for (int t = 0; t < 4; ++t) {                 // A: 256 rows x 128B = 32KB
            const int q = t * 8192 + tid * 16;
            const int r = q >> 7;
            const int bsw = (q & 127) ^ ((r & 7) << 4);
            const unsigned short* src = (bsw < 64)
                ? xh + (size_t)(row0 + r) * NDIM + kk + (bsw >> 1)
                : xl + (size_t)(row0 + r) * NDIM + kk + ((bsw - 64) >> 1);
            gl_lds16(src, lds + q);
        }
        #pragma unroll
        for (int t = 0; t < 4; ++t) {                 // B: 256 rows x 128B = 32KB
            const int q = t * 8192 + tid * 16;
            const int r = q >> 7;
            const int bsw = (q & 127) ^ ((r & 7) << 4);
            const unsigned short* src = (bsw < 64)
                ? Mth + (size_t)(colbase + r) * NDIM + kk + (bsw >> 1)
                : Mtl + (size_t)(colbase + r) * NDIM + kk + ((bsw - 64) >> 1);
            gl_lds16(src, lds + 32768 + q);
        }
        __syncthreads();
        const int bq = (l >> 4) * 16;
        f16x8 ah[4], al[4];
        #pragma unroll
        for (int mi = 0; mi < 4; ++mi) {
            const int ra = wr * 64 + mi * 16 + (l & 15);
            const int sz = (ra & 7) << 4;
            ah[mi] = *(const f16x8*)(lds + ra * 128 + (bq ^ sz));
            al[mi] = *(const f16x8*)(lds + ra * 128 + ((bq + 64) ^ sz));
        }
        __builtin_amdgcn_s_setprio(1);
        #pragma unroll
        for (int nj = 0; nj < 8; ++nj) {
            const int rb = wc * 128 + nj * 16 + (l & 15);
            const int sz = (rb & 7) << 4;
            f16x8 bh = *(const f16x8*)(lds + 32768 + rb * 128 + (bq ^ sz));
            f16x8 bl = *(const f16x8*)(lds + 32768 + rb * 128 + ((bq + 64) ^ sz));
            #pragma unroll
            for (int mi = 0; mi < 4; ++mi) {
                acc[mi][nj] = __builtin_amdgcn_mfma_f32_16x16x32_f16(ah[mi], bh, acc[mi][nj], 0, 0, 0);
                acc[mi][nj] = __builtin_amdgcn_mfma_f32_16x16x32_f16(ah[mi], bl, acc[mi][nj], 0, 0, 0);
                acc[mi][nj] = __builtin_amdgcn_mfma_f32_16x16x32_f16(al[mi], bh, acc[mi][nj], 0, 0, 0);
            }
        }
        __builtin_amdgcn_s_setprio(0);
    }
    __syncthreads();

    if (by == 16) {     // D strip: cols 4096..4351
        #pragma unroll
        for (int mi = 0; mi < 4; ++mi)
            #pragma unroll
            for (int nj = 0; nj < 8; ++nj)
                #pragma unroll
                for (int r = 0; r < 4; ++r) {
                    const int row = row0 + wr * 64 + mi * 16 + (l >> 4) * 4 + r;
                    const int col = wc * 128 + nj * 16 + (l & 15);
                    D[(size_t)row * 256 + col] = acc[mi][nj][r];
                }
        return;
    }

    // epilogue: 8 chunks of 32 rows; Cl[32][260] = 33.3KB. Chunk c rows
    // [c*32,+32): waves wr == c>>1, mi = (c&1)*2 + u.
    float* Cl = (float*)lds;
    const int g2 = tid >> 4;           // 0..31
    const int lam = tid & 15;
    for (int c = 0; c < 8; ++c) {
        if (wr == (c >> 1)) {
            #pragma unroll
            for (int u = 0; u < 2; ++u) {
                const int mi = (c & 1) * 2 + u;
                #pragma unroll
                for (int nj = 0; nj < 8; ++nj)
                    #pragma unroll
                    for (int r = 0; r < 4; ++r)
                        Cl[(u * 16 + (l >> 4) * 4 + r) * 260 + wc * 128 + nj * 16 + (l & 15)] =
                            acc[mi][nj][r];
            }
        }
        __syncthreads();
        {
            float v[16];
            #pragma unroll
            for (int j = 0; j < 16; ++j) v[j] = Cl[g2 * 260 + lam + 16 * j];
            // in-lane bitonic sort ascending
            #pragma unroll
            for (int k = 2; k <= 16; k <<= 1)
                #pragma unroll
                for (int j = k >> 1; j > 0; j >>= 1)
                    #pragma unroll
                    for (int i = 0; i < 16; ++i) {
                        const int l2 = i ^ j;
                        if (l2 > i) {
                            const bool asc = ((i & k) == 0);
                            const float lo = fminf(v[i], v[l2]), hi = fmaxf(v[i], v[l2]);
                            v[i] = asc ? lo : hi;
                            v[l2] = asc ? hi : lo;
                        }
                    }
            // 4 cross-lane merge levels within 16-lane group
            #pragma unroll
            for (int lvl = 1; lvl <= 8; lvl <<= 1) {
                float m[16];
                #pragma unroll
                for (int q = 0; q < 16; ++q)
                    m[q] = fmaxf(v[q], __shfl_xor(v[15 - q], lvl));
                #pragma unroll
                for (int j = 8; j > 0; j >>= 1)
                    #pragma unroll
                    for (int i = 0; i < 16; ++i) {
                        const int l2 = i ^ j;
                        if (l2 > i) {
                            const float lo = fminf(m[i], m[l2]), hi = fmaxf(m[i], m[l2]);
                            m[i] = lo; m[l2] = hi;
                        }
                    }
                #pragma unroll
                for (int q = 0; q < 16; ++q) v[q] = m[q];
            }
            const int n = row0 + c * 32 + g2;
            T[((size_t)n * 16 + by) * 16 + lam] = v[15 - lam];
        }
        __syncthreads();
    }
}

// ---------------- kC: 50 monotone candidates -> top-16 -> softmax*gelu(D) -> W fp16
__device__ const unsigned short CAND_TBL[32] = {
    0x0100, 0x0302, 0x0504, 0x0706, 0x0908, 0x0B0A, 0x0D0C, 0x0F0E,
    0x1110, 0x1312, 0x1514, 0x1716,
    0x2120, 0x2322, 0x3024, 0x3231, 0x4033, 0x4241,
    0x5150, 0x6160, 0x7170,
    0x9080, 0xB0A0, 0xD0C0, 0xF0E0,
    0xFFFF, 0xFFFF, 0xFFFF, 0xFFFF, 0xFFFF, 0xFFFF, 0xFFFF
};

__device__ __forceinline__ float sel16(const float a[16], int i) {
    float b0 = (i & 1) ? a[1] : a[0];
    float b1 = (i & 1) ? a[3] : a[2];
    float b2 = (i & 1) ? a[5] : a[4];
    float b3 = (i & 1) ? a[7] : a[6];
    float b4 = (i & 1) ? a[9] : a[8];
    float b5 = (i & 1) ? a[11] : a[10];
    float b6 = (i & 1) ? a[13] : a[12];
    float b7 = (i & 1) ? a[15] : a[14];
    float c0 = (i & 2) ? b1 : b0;
    float c1 = (i & 2) ? b3 : b2;
    float c2 = (i & 2) ? b5 : b4;
    float c3 = (i & 2) ? b7 : b6;
    float d0 = (i & 4) ? c1 : c0;
    float d1 = (i & 4) ? c3 : c2;
    return (i & 8) ? d1 : d0;
}

__global__ __launch_bounds__(256) void kC_combine(const float* __restrict__ T,
                                                  const float* __restrict__ D,
                                                  unsigned short* __restrict__ Wh,
                                                  unsigned short* __restrict__ Wl) {
    __shared__ unsigned long long ckey[8][50];
    __shared__ float winval[8][16];
    __shared__ int winflat[8][16];
    __shared__ int Wrow[256];

    const int tid = threadIdx.x;
    const int n = blockIdx.x;
    const int h = tid >> 5;
    const int lam = tid & 15;

    Wrow[tid] = 0;

    float sxd[16], syd[16];
    const float* t0 = &T[((size_t)n * 16 + h) * 16];
    const float* t1 = &T[((size_t)n * 16 + 8 + h) * 16];
    #pragma unroll
    for (int q = 0; q < 16; ++q) { sxd[q] = t0[q]; syd[q] = t1[q]; }

    const int lc = tid & 31;
    const unsigned int cw = CAND_TBL[lc];
    unsigned long long mykey[2]; float myval[2]; int myflat[2]; int myrank[2] = {0, 0};
    #pragma unroll
    for (int u = 0; u < 2; ++u) {
        const int fl = (cw >> (8 * u)) & 0xFF;
        const float sv = sel16(sxd, fl >> 4) + sel16(syd, fl & 15);
        const unsigned int uv = __float_as_uint(sv);
        const unsigned int mo = (uv & 0x80000000u) ? ~uv : (uv | 0x80000000u);
        mykey[u] = ((unsigned long long)mo << 8) | (unsigned long long)(255 - fl);
        myval[u] = sv; myflat[u] = fl;
        const int slot = lc * 2 + u;
        if (slot < 50) ckey[h][slot] = mykey[u];
    }
    __syncthreads();
    for (int kk = 0; kk < 50; ++kk) {
        const unsigned long long ok = ckey[h][kk];
        myrank[0] += (ok > mykey[0]) ? 1 : 0;
        myrank[1] += (ok > mykey[1]) ? 1 : 0;
    }
    #pragma unroll
    for (int u = 0; u < 2; ++u)
        if (myrank[u] < 16) { winval[h][myrank[u]] = myval[u]; winflat[h][myrank[u]] = myflat[u]; }
    __syncthreads();

    if (!(tid & 16)) {
        const float sc = winval[h][lam];
        const float m0 = winval[h][0];
        float e = expf(sc - m0);
        float esum = e;
        #pragma unroll
        for (int off = 1; off < 16; off <<= 1) esum += __shfl_xor(esum, off);
        const int fl = winflat[h][lam];
        const float hv = D[(size_t)n * 256 + fl];
        const float gg = 0.5f * hv * (1.0f + erff(hv * 0.70710678118654752f));
        const float wv = (e / esum) * gg;
        atomicAdd(&Wrow[fl], __float2int_rn(wv * 4194304.0f));
    }
    __syncthreads();
    const float wfin = (float)Wrow[tid] * (1.0f / 4194304.0f);
    const unsigned short hh = f32_to_f16(wfin);
    Wh[(size_t)n * 256 + tid] = hh;
    Wl[(size_t)n * 256 + tid] = f32_to_f16((wfin - f16_to_f32(hh)) * LSC);
}

// ---------------- k5: out = W @ up256, scaled-lo dual-acc
__global__ __launch_bounds__(256) void k5_mfma(const unsigned short* __restrict__ Wh,
                                               const unsigned short* __restrict__ Wl,
                                               const unsigned short* __restrict__ upTh,
                                               const unsigned short* __restrict__ upTl,
                                               float* __restrict__ out) {
    __shared__ __align__(16) char lds[20480];   // A 4KB + B 16KB
    const int tid = threadIdx.x;
    const int w = tid >> 6, l = tid & 63;
    const int n0 = blockIdx.x * 32;
    const int d0 = blockIdx.y * 128;
    f32x4 acch[2][2] = {};
    f32x4 accl[2][2] = {};

    for (int s = 0; s < 8; ++s) {
        const int kk = s * 32;
        __syncthreads();
        {   // A: W rows 32 x 128B = 4KB
            const int q = w * 1024 + l * 16;
            const int r = q >> 7;
            const int bsw = (q & 127) ^ ((r & 7) << 4);
            const unsigned short* src = (bsw < 64)
                ? Wh + (size_t)(n0 + r) * 256 + kk + (bsw >> 1)
                : Wl + (size_t)(n0 + r) * 256 + kk + ((bsw - 64) >> 1);
            gl_lds16(src, lds + w * 1024);
        }
        #pragma unroll
        for (int t = 0; t < 4; ++t) {   // B: upT rows 128 x 128B = 16KB
            const int q = w * 4096 + t * 1024 + l * 16;
            const int r = q >> 7;
            const int bsw = (q & 127) ^ ((r & 7) << 4);
            const unsigned short* src = (bsw < 64)
                ? upTh + (size_t)(d0 + r) * 256 + kk + (bsw >> 1)
                : upTl + (size_t)(d0 + r) * 256 + kk + ((bsw - 64) >> 1);
            gl_lds16(src, lds + 4096 + w * 4096 + t * 1024);
        }
        __syncthreads();
        const int bq = (l >> 4) * 16;
        f16x8 ah[2], al[2];
        #pragma unroll
        for (int mi = 0; mi < 2; ++mi) {
            const int ra = mi * 16 + (l & 15);
            const int swz = (ra & 7) << 4;
            ah[mi] = *(const f16x8*)(lds + ra * 128 + (bq ^ swz));
            al[mi] = *(const f16x8*)(lds + ra * 128 + ((bq + 64) ^ swz));
        }
        #pragma unroll
        for (int nj = 0; nj < 2; ++nj) {
            const int rb = w * 32 + nj * 16 + (l & 15);
            const int swz = (rb & 7) << 4;
            f16x8 bh = *(const f16x8*)(lds + 4096 + rb * 128 + (bq ^ swz));
            f16x8 bl = *(const f16x8*)(lds + 4096 + rb * 128 + ((bq + 64) ^ swz));
            #pragma unroll
            for (int mi = 0; mi < 2; ++mi) {
                acch[mi][nj] = __builtin_amdgcn_mfma_f32_16x16x32_f16(ah[mi], bh, acch[mi][nj], 0, 0, 0);
                accl[mi][nj] = __builtin_amdgcn_mfma_f32_16x16x32_f16(ah[mi], bl, accl[mi][nj], 0, 0, 0);
                accl[mi][nj] = __builtin_amdgcn_mfma_f32_16x16x32_f16(al[mi], bh, accl[mi][nj], 0, 0, 0);
            }
        }
    }
    #pragma unroll
    for (int mi = 0; mi < 2; ++mi)
        #pragma unroll
        for (int nj = 0; nj < 2; ++nj)
            #pragma unroll
            for (int r = 0; r < 4; ++r) {
                const int row = n0 + mi * 16 + (l >> 4) * 4 + r;
                const int col = d0 + w * 32 + nj * 16 + (l & 15);
                out[(size_t)row * NDIM + col] = fmaf(accl[mi][nj][r], ILSC, acch[mi][nj][r]);
            }
}

extern "C" void kernel_launch(void* const* d_in, const int* in_sizes, int n_in,
                              void* d_out, int out_size, void* d_ws, size_t ws_size,
                              hipStream_t stream) {
    const float* x    = (const float*)d_in[0];
    const float* Wq   = (const float*)d_in[1];
    const float* keys = (const float*)d_in[2];
    const float* down = (const float*)d_in[3];
    const float* up   = (const float*)d_in[4];
    float* out = (float*)d_out;

    char* ws = (char*)d_ws;
    unsigned short* Mth  = (unsigned short*)(ws);                  // 4,456,448 B
    unsigned short* Mtl  = (unsigned short*)(ws + 4456448);        // 4,456,448 B
    unsigned short* xh   = (unsigned short*)(ws + 8912896);        // 2,097,152 B
    unsigned short* xl   = (unsigned short*)(ws + 11010048);       // 2,097,152 B
    unsigned short* Wqh  = (unsigned short*)(ws + 13107200);       // 4,194,304 B
    unsigned short* Wql  = (unsigned short*)(ws + 17301504);       // 4,194,304 B
    unsigned short* ksh  = (unsigned short*)(ws + 21495808);       // 2,097,152 B
    unsigned short* ksl  = (unsigned short*)(ws + 23592960);       // 2,097,152 B
    unsigned short* upTh = (unsigned short*)(ws + 25690112);       //   262,144 B
    unsigned short* upTl = (unsigned short*)(ws + 25952256);       //   262,144 B
    float* T             = (float*)(ws + 26214400);                // 2,097,152 B
    float* D             = (float*)(ws + 30408704);                // 2,097,152 B
    unsigned short* Wh   = (unsigned short*)(ws + 32505856);       // 1,048,576 B
    unsigned short* Wl   = (unsigned short*)(ws + 33554432);       // 1,048,576 B

    kP_split<<<1344, 256, 0, stream>>>(x, Wq, keys, down, up,
                                       xh, xl, Wqh, Wql, ksh, ksl, Mth, Mtl, upTh, upTl);
    kQ_m1<<<dim3(16, 16), 256, 0, stream>>>(Wqh, Wql, ksh, ksl, Mth, Mtl);
    kF_gemm<<<136, 512, 0, stream>>>(xh, xl, Mth, Mtl, T, D);
    kC_combine<<<2048, 256, 0, stream>>>(T, D, Wh, Wl);
    k5_mfma<<<dim3(64, 4), 256, 0, stream>>>(Wh, Wl, upTh, upTl, out);
}

// Round 19
// 120.114 us; speedup vs baseline: 2.9904x; 2.9904x over previous
//
#include <hip/hip_runtime.h>
#include <math.h>

#define N_TOK 2048
#define NDIM 512
#define HEADS 8
#define TOPK 16
#define QCOLS 4096
#define LSC 4096.0f          // scaled-lo (kQ/k5/W paths only)
#define ILSC (1.0f/4096.0f)

typedef __attribute__((ext_vector_type(8))) _Float16 f16x8;
typedef __attribute__((ext_vector_type(4))) float f32x4;

__device__ __forceinline__ unsigned short f32_to_f16(float f) {
    _Float16 h = (_Float16)f;
    return __builtin_bit_cast(unsigned short, h);
}
__device__ __forceinline__ float f16_to_f32(unsigned short u) {
    return (float)__builtin_bit_cast(_Float16, u);
}
__device__ __forceinline__ void gl_lds16(const void* g, void* l) {
    __builtin_amdgcn_global_load_lds(
        (const __attribute__((address_space(1))) void*)g,
        (__attribute__((address_space(3))) void*)l, 16, 0, 0);
}

// ---------------- kP: splits. x/down -> UNSCALED lo (kF single-acc);
// Wq/keys/upT -> scaled lo (kQ/k5 dual-acc).
__device__ __forceinline__ void split_f4s(const float* __restrict__ src,
                                          unsigned short* __restrict__ dh,
                                          unsigned short* __restrict__ dl,
                                          int i, float lsc) {
    float4 v = reinterpret_cast<const float4*>(src)[i];
    float vv[4] = {v.x, v.y, v.z, v.w};
    ushort4 h, lo;
    unsigned short* hp = &h.x; unsigned short* lp = &lo.x;
    #pragma unroll
    for (int q = 0; q < 4; ++q) {
        unsigned short hh = f32_to_f16(vv[q]);
        hp[q] = hh;
        lp[q] = f32_to_f16((vv[q] - f16_to_f32(hh)) * lsc);
    }
    reinterpret_cast<ushort4*>(dh)[i] = h;
    reinterpret_cast<ushort4*>(dl)[i] = lo;
}

__global__ __launch_bounds__(256) void kP_split(const float* __restrict__ x,
                                                const float* __restrict__ Wq,
                                                const float* __restrict__ keys,
                                                const float* __restrict__ down,
                                                const float* __restrict__ up,
                                                unsigned short* __restrict__ xh,
                                                unsigned short* __restrict__ xl,
                                                unsigned short* __restrict__ Wqh,
                                                unsigned short* __restrict__ Wql,
                                                unsigned short* __restrict__ ksh,
                                                unsigned short* __restrict__ ksl,
                                                unsigned short* __restrict__ Mth,
                                                unsigned short* __restrict__ Mtl,
                                                unsigned short* __restrict__ upTh,
                                                unsigned short* __restrict__ upTl) {
    const int bid = blockIdx.x;
    const int tid = threadIdx.x;
    if (bid < 256) {                     // x: unscaled lo
        #pragma unroll
        for (int t = 0; t < 4; ++t) split_f4s(x, xh, xl, bid * 1024 + t * 256 + tid, 1.0f);
        return;
    }
    if (bid < 768) {                     // Wq: scaled lo
        const int b = bid - 256;
        #pragma unroll
        for (int t = 0; t < 4; ++t) split_f4s(Wq, Wqh, Wql, b * 1024 + t * 256 + tid, LSC);
        return;
    }
    if (bid < 1024) {                    // keys: scaled lo
        const int b = bid - 768;
        #pragma unroll
        for (int t = 0; t < 4; ++t) split_f4s(keys, ksh, ksl, b * 1024 + t * 256 + tid, LSC);
        return;
    }
    if (bid < 1280) {                    // down row e -> Mt row 4096+e (UNSCALED lo)
        const int e = bid - 1024;
        const int d0 = tid * 2;
        float2 v = *reinterpret_cast<const float2*>(&down[(size_t)e * NDIM + d0]);
        ushort2 h, lo;
        unsigned short h0 = f32_to_f16(v.x);
        unsigned short h1 = f32_to_f16(v.y);
        h.x = h0; h.y = h1;
        lo.x = f32_to_f16(v.x - f16_to_f32(h0));
        lo.y = f32_to_f16(v.y - f16_to_f32(h1));
        *reinterpret_cast<ushort2*>(&Mth[(size_t)(QCOLS + e) * NDIM + d0]) = h;
        *reinterpret_cast<ushort2*>(&Mtl[(size_t)(QCOLS + e) * NDIM + d0]) = lo;
        return;
    }
    // upT: scaled lo (k5 path)
    const int b = bid - 1280;
    #pragma unroll
    for (int dd = 0; dd < 8; ++dd) {
        const int d = b * 8 + dd;
        const int e = tid;
        const float v = up[(size_t)e * NDIM + d];
        unsigned short hh = f32_to_f16(v);
        upTh[(size_t)d * 256 + e] = hh;
        upTl[(size_t)d * 256 + e] = f32_to_f16((v - f16_to_f32(hh)) * LSC);
    }
}

// ---------------- kQ: M = Wq_slice @ keys^T (scaled-lo dual-acc), emits Mt with
// UNSCALED lo (kF consumes). grid (16,16).
__global__ __launch_bounds__(256) void kQ_m1(const unsigned short* __restrict__ Wqh,
                                             const unsigned short* __restrict__ Wql,
                                             const unsigned short* __restrict__ ksh,
                                             const unsigned short* __restrict__ ksl,
                                             unsigned short* __restrict__ Mth,
                                             unsigned short* __restrict__ Mtl) {
    __shared__ __align__(16) char lds[36864];   // A 4KB + B 32KB
    const int tid = threadIdx.x;
    const int w = tid >> 6, l = tid & 63;
    const int c0 = blockIdx.x * 32;
    const int ph = blockIdx.y;
    const int p = ph >> 3, h = ph & 7;
    const int off = p * 2048 + h * 256;
    f32x4 acch[2][4] = {};
    f32x4 accl[2][4] = {};

    for (int s = 0; s < 8; ++s) {
        const int kk = s * 32;
        __syncthreads();
        {   // A: 32 rows x 128B = 4KB
            const int q = w * 1024 + l * 16;
            const int r = q >> 7;
            const int bsw = (q & 127) ^ ((r & 7) << 4);
            const unsigned short* src = (bsw < 64)
                ? Wqh + (size_t)(c0 + r) * QCOLS + off + kk + (bsw >> 1)
                : Wql + (size_t)(c0 + r) * QCOLS + off + kk + ((bsw - 64) >> 1);
            gl_lds16(src, lds + w * 1024);
        }
        #pragma unroll
        for (int t = 0; t < 8; ++t) {   // B: 256 rows x 128B = 32KB
            const int q = w * 8192 + t * 1024 + l * 16;
            const int r = q >> 7;
            const int bsw = (q & 127) ^ ((r & 7) << 4);
            const unsigned short* src = (bsw < 64)
                ? ksh + ((size_t)(h * 256 + r) * 2 + p) * 256 + kk + (bsw >> 1)
                : ksl + ((size_t)(h * 256 + r) * 2 + p) * 256 + kk + ((bsw - 64) >> 1);
            gl_lds16(src, lds + 4096 + w * 8192 + t * 1024);
        }
        __syncthreads();
        const int bq = (l >> 4) * 16;
        f16x8 ah[2], al[2];
        #pragma unroll
        for (int mi = 0; mi < 2; ++mi) {
            const int ra = mi * 16 + (l & 15);
            const int swz = (ra & 7) << 4;
            ah[mi] = *(const f16x8*)(lds + ra * 128 + (bq ^ swz));
            al[mi] = *(const f16x8*)(lds + ra * 128 + ((bq + 64) ^ swz));
        }
        __builtin_amdgcn_s_setprio(1);
        #pragma unroll
        for (int nj = 0; nj < 4; ++nj) {
            const int rb = w * 64 + nj * 16 + (l & 15);
            const int swz = (rb & 7) << 4;
            f16x8 bh = *(const f16x8*)(lds + 4096 + rb * 128 + (bq ^ swz));
            f16x8 bl = *(const f16x8*)(lds + 4096 + rb * 128 + ((bq + 64) ^ swz));
            #pragma unroll
            for (int mi = 0; mi < 2; ++mi) {
                acch[mi][nj] = __builtin_amdgcn_mfma_f32_16x16x32_f16(ah[mi], bh, acch[mi][nj], 0, 0, 0);
                accl[mi][nj] = __builtin_amdgcn_mfma_f32_16x16x32_f16(ah[mi], bl, accl[mi][nj], 0, 0, 0);
                accl[mi][nj] = __builtin_amdgcn_mfma_f32_16x16x32_f16(al[mi], bh, accl[mi][nj], 0, 0, 0);
            }
        }
        __builtin_amdgcn_s_setprio(0);
    }
    #pragma unroll
    for (int mi = 0; mi < 2; ++mi)
        #pragma unroll
        for (int nj = 0; nj < 4; ++nj) {
            const int k = w * 64 + nj * 16 + (l & 15);
            const int cb = c0 + mi * 16 + (l >> 4) * 4;
            ushort4 h4, l4;
            unsigned short* hp = &h4.x; unsigned short* lp = &l4.x;
            #pragma unroll
            for (int r = 0; r < 4; ++r) {
                const float v = fmaf(accl[mi][nj][r], ILSC, acch[mi][nj][r]);
                unsigned short hh = f32_to_f16(v);
                hp[r] = hh;
                lp[r] = f32_to_f16(v - f16_to_f32(hh));   // UNSCALED lo for kF
            }
            *reinterpret_cast<ushort4*>(&Mth[(size_t)(off + k) * NDIM + cb]) = h4;
            *reinterpret_cast<ushort4*>(&Mtl[(size_t)(off + k) * NDIM + cb]) = l4;
        }
}

// ---------------- kF: BM=BN=256, BK=32, 512 threads (8 waves, 4x2; 64x128 tiles),
// single acc chain, 64KB LDS single-buffer. Grid 136: XCD k owns row-tile k.
// Epilogue chunk loop FULLY UNROLLED (rule #20: runtime acc index -> scratch spill,
// the R17/R18 bug: VGPR=52 + 594MB scratch WRITE_SIZE).
#define BM 256
#define BN 256
#define BK 32
__global__ __launch_bounds__(512, 2) void kF_gemm(const unsigned short* __restrict__ xh,
                                                  const unsigned short* __restrict__ xl,
                                                  const unsigned short* __restrict__ Mth,
                                                  const unsigned short* __restrict__ Mtl,
                                                  float* __restrict__ T,
                                                  float* __restrict__ D) {
    __shared__ __align__(16) char lds[65536];   // A 32KB + B 32KB
    const int tid = threadIdx.x;
    const int w = tid >> 6, l = tid & 63;
    const int wr = w >> 1, wc = w & 1;          // 4x2 wave grid: 64-row x 128-col tiles
    const int orig = blockIdx.x;                // 0..135
    const int swz = (orig & 7) * 17 + (orig >> 3);  // bijective (136 = 8*17)
    const int rt = swz / 17;                    // row-tile 0..7
    const int by = swz % 17;                    // col strip 0..16
    const int row0 = rt * BM;
    const int colbase = by * 256;
    f32x4 acc[4][8] = {};

    for (int s = 0; s < 16; ++s) {
        const int kk = s * BK;
        __syncthreads();
        #pragma unroll
        for (int t = 0; t < 4; ++t) {                 // A: 256 rows x 128B = 32KB
            const int q = t * 8192 + tid * 16;
            const int r = q >> 7;
            const int bsw = (q & 127) ^ ((r & 7) << 4);
            const unsigned short* src = (bsw < 64)
                ? xh + (size_t)(row0 + r) * NDIM + kk + (bsw >> 1)
                : xl + (size_t)(row0 + r) * NDIM + kk + ((bsw - 64) >> 1);
            gl_lds16(src, lds + q);
        }
        #pragma unroll
        for (int t = 0; t < 4; ++t) {                 // B: 256 rows x 128B = 32KB
            const int q = t * 8192 + tid * 16;
            const int r = q >> 7;
            const int bsw = (q & 127) ^ ((r & 7) << 4);
            const unsigned short* src = (bsw < 64)
                ? Mth + (size_t)(colbase + r) * NDIM + kk + (bsw >> 1)
                : Mtl + (size_t)(colbase + r) * NDIM + kk + ((bsw - 64) >> 1);
            gl_lds16(src, lds + 32768 + q);
        }
        __syncthreads();
        const int bq = (l >> 4) * 16;
        f16x8 ah[4], al[4];
        #pragma unroll
        for (int mi = 0; mi < 4; ++mi) {
            const int ra = wr * 64 + mi * 16 + (l & 15);
            const int sz = (ra & 7) << 4;
            ah[mi] = *(const f16x8*)(lds + ra * 128 + (bq ^ sz));
            al[mi] = *(const f16x8*)(lds + ra * 128 + ((bq + 64) ^ sz));
        }
        __builtin_amdgcn_s_setprio(1);
        #pragma unroll
        for (int nj = 0; nj < 8; ++nj) {
            const int rb = wc * 128 + nj * 16 + (l & 15);
            const int sz = (rb & 7) << 4;
            f16x8 bh = *(const f16x8*)(lds + 32768 + rb * 128 + (bq ^ sz));
            f16x8 bl = *(const f16x8*)(lds + 32768 + rb * 128 + ((bq + 64) ^ sz));
            #pragma unroll
            for (int mi = 0; mi < 4; ++mi) {
                acc[mi][nj] = __builtin_amdgcn_mfma_f32_16x16x32_f16(ah[mi], bh, acc[mi][nj], 0, 0, 0);
                acc[mi][nj] = __builtin_amdgcn_mfma_f32_16x16x32_f16(ah[mi], bl, acc[mi][nj], 0, 0, 0);
                acc[mi][nj] = __builtin_amdgcn_mfma_f32_16x16x32_f16(al[mi], bh, acc[mi][nj], 0, 0, 0);
            }
        }
        __builtin_amdgcn_s_setprio(0);
    }
    __syncthreads();

    if (by == 16) {     // D strip: cols 4096..4351
        #pragma unroll
        for (int mi = 0; mi < 4; ++mi)
            #pragma unroll
            for (int nj = 0; nj < 8; ++nj)
                #pragma unroll
                for (int r = 0; r < 4; ++r) {
                    const int row = row0 + wr * 64 + mi * 16 + (l >> 4) * 4 + r;
                    const int col = wc * 128 + nj * 16 + (l & 15);
                    D[(size_t)row * 256 + col] = acc[mi][nj][r];
                }
        return;
    }

    // epilogue: 8 chunks of 32 rows; Cl[32][260] = 33.3KB. UNROLLED (rule #20).
    float* Cl = (float*)lds;
    const int g2 = tid >> 4;           // 0..31
    const int lam = tid & 15;
    #pragma unroll
    for (int c = 0; c < 8; ++c) {
        if (wr == (c >> 1)) {
            #pragma unroll
            for (int u = 0; u < 2; ++u) {
                const int mi = (c & 1) * 2 + u;
                #pragma unroll
                for (int nj = 0; nj < 8; ++nj)
                    #pragma unroll
                    for (int r = 0; r < 4; ++r)
                        Cl[(u * 16 + (l >> 4) * 4 + r) * 260 + wc * 128 + nj * 16 + (l & 15)] =
                            acc[mi][nj][r];
            }
        }
        __syncthreads();
        {
            float v[16];
            #pragma unroll
            for (int j = 0; j < 16; ++j) v[j] = Cl[g2 * 260 + lam + 16 * j];
            // in-lane bitonic sort ascending
            #pragma unroll
            for (int k = 2; k <= 16; k <<= 1)
                #pragma unroll
                for (int j = k >> 1; j > 0; j >>= 1)
                    #pragma unroll
                    for (int i = 0; i < 16; ++i) {
                        const int l2 = i ^ j;
                        if (l2 > i) {
                            const bool asc = ((i & k) == 0);
                            const float lo = fminf(v[i], v[l2]), hi = fmaxf(v[i], v[l2]);
                            v[i] = asc ? lo : hi;
                            v[l2] = asc ? hi : lo;
                        }
                    }
            // 4 cross-lane merge levels within 16-lane group
            #pragma unroll
            for (int lvl = 1; lvl <= 8; lvl <<= 1) {
                float m[16];
                #pragma unroll
                for (int q = 0; q < 16; ++q)
                    m[q] = fmaxf(v[q], __shfl_xor(v[15 - q], lvl));
                #pragma unroll
                for (int j = 8; j > 0; j >>= 1)
                    #pragma unroll
                    for (int i = 0; i < 16; ++i) {
                        const int l2 = i ^ j;
                        if (l2 > i) {
                            const float lo = fminf(m[i], m[l2]), hi = fmaxf(m[i], m[l2]);
                            m[i] = lo; m[l2] = hi;
                        }
                    }
                #pragma unroll
                for (int q = 0; q < 16; ++q) v[q] = m[q];
            }
            const int n = row0 + c * 32 + g2;
            T[((size_t)n * 16 + by) * 16 + lam] = v[15 - lam];
        }
        __syncthreads();
    }
}

// ---------------- kC: 50 monotone candidates -> top-16 -> softmax*gelu(D) -> W fp16
__device__ const unsigned short CAND_TBL[32] = {
    0x0100, 0x0302, 0x0504, 0x0706, 0x0908, 0x0B0A, 0x0D0C, 0x0F0E,
    0x1110, 0x1312, 0x1514, 0x1716,
    0x2120, 0x2322, 0x3024, 0x3231, 0x4033, 0x4241,
    0x5150, 0x6160, 0x7170,
    0x9080, 0xB0A0, 0xD0C0, 0xF0E0,
    0xFFFF, 0xFFFF, 0xFFFF, 0xFFFF, 0xFFFF, 0xFFFF, 0xFFFF
};

__device__ __forceinline__ float sel16(const float a[16], int i) {
    float b0 = (i & 1) ? a[1] : a[0];
    float b1 = (i & 1) ? a[3] : a[2];
    float b2 = (i & 1) ? a[5] : a[4];
    float b3 = (i & 1) ? a[7] : a[6];
    float b4 = (i & 1) ? a[9] : a[8];
    float b5 = (i & 1) ? a[11] : a[10];
    float b6 = (i & 1) ? a[13] : a[12];
    float b7 = (i & 1) ? a[15] : a[14];
    float c0 = (i & 2) ? b1 : b0;
    float c1 = (i & 2) ? b3 : b2;
    float c2 = (i & 2) ? b5 : b4;
    float c3 = (i & 2) ? b7 : b6;
    float d0 = (i & 4) ? c1 : c0;
    float d1 = (i & 4) ? c3 : c2;
    return (i & 8) ? d1 : d0;
}

__global__ __launch_bounds__(256) void kC_combine(const float* __restrict__ T,
                                                  const float* __restrict__ D,
                                                  unsigned short* __restrict__ Wh,
                                                  unsigned short* __restrict__ Wl) {
    __shared__ unsigned long long ckey[8][50];
    __shared__ float winval[8][16];
    __shared__ int winflat[8][16];
    __shared__ int Wrow[256];

    const int tid = threadIdx.x;
    const int n = blockIdx.x;
    const int h = tid >> 5;
    const int lam = tid & 15;

    Wrow[tid] = 0;

    float sxd[16], syd[16];
    const float* t0 = &T[((size_t)n * 16 + h) * 16];
    const float* t1 = &T[((size_t)n * 16 + 8 + h) * 16];
    #pragma unroll
    for (int q = 0; q < 16; ++q) { sxd[q] = t0[q]; syd[q] = t1[q]; }

    const int lc = tid & 31;
    const unsigned int cw = CAND_TBL[lc];
    unsigned long long mykey[2]; float myval[2]; int myflat[2]; int myrank[2] = {0, 0};
    #pragma unroll
    for (int u = 0; u < 2; ++u) {
        const int fl = (cw >> (8 * u)) & 0xFF;
        const float sv = sel16(sxd, fl >> 4) + sel16(syd, fl & 15);
        const unsigned int uv = __float_as_uint(sv);
        const unsigned int mo = (uv & 0x80000000u) ? ~uv : (uv | 0x80000000u);
        mykey[u] = ((unsigned long long)mo << 8) | (unsigned long long)(255 - fl);
        myval[u] = sv; myflat[u] = fl;
        const int slot = lc * 2 + u;
        if (slot < 50) ckey[h][slot] = mykey[u];
    }
    __syncthreads();
    for (int kk = 0; kk < 50; ++kk) {
        const unsigned long long ok = ckey[h][kk];
        myrank[0] += (ok > mykey[0]) ? 1 : 0;
        myrank[1] += (ok > mykey[1]) ? 1 : 0;
    }
    #pragma unroll
    for (int u = 0; u < 2; ++u)
        if (myrank[u] < 16) { winval[h][myrank[u]] = myval[u]; winflat[h][myrank[u]] = myflat[u]; }
    __syncthreads();

    if (!(tid & 16)) {
        const float sc = winval[h][lam];
        const float m0 = winval[h][0];
        float e = expf(sc - m0);
        float esum = e;
        #pragma unroll
        for (int off = 1; off < 16; off <<= 1) esum += __shfl_xor(esum, off);
        const int fl = winflat[h][lam];
        const float hv = D[(size_t)n * 256 + fl];
        const float gg = 0.5f * hv * (1.0f + erff(hv * 0.70710678118654752f));
        const float wv = (e / esum) * gg;
        atomicAdd(&Wrow[fl], __float2int_rn(wv * 4194304.0f));
    }
    __syncthreads();
    const float wfin = (float)Wrow[tid] * (1.0f / 4194304.0f);
    const unsigned short hh = f32_to_f16(wfin);
    Wh[(size_t)n * 256 + tid] = hh;
    Wl[(size_t)n * 256 + tid] = f32_to_f16((wfin - f16_to_f32(hh)) * LSC);
}

// ---------------- k5: out = W @ up256, scaled-lo dual-acc
__global__ __launch_bounds__(256) void k5_mfma(const unsigned short* __restrict__ Wh,
                                               const unsigned short* __restrict__ Wl,
                                               const unsigned short* __restrict__ upTh,
                                               const unsigned short* __restrict__ upTl,
                                               float* __restrict__ out) {
    __shared__ __align__(16) char lds[20480];   // A 4KB + B 16KB
    const int tid = threadIdx.x;
    const int w = tid >> 6, l = tid & 63;
    const int n0 = blockIdx.x * 32;
    const int d0 = blockIdx.y * 128;
    f32x4 acch[2][2] = {};
    f32x4 accl[2][2] = {};

    for (int s = 0; s < 8; ++s) {
        const int kk = s * 32;
        __syncthreads();
        {   // A: W rows 32 x 128B = 4KB
            const int q = w * 1024 + l * 16;
            const int r = q >> 7;
            const int bsw = (q & 127) ^ ((r & 7) << 4);
            const unsigned short* src = (bsw < 64)
                ? Wh + (size_t)(n0 + r) * 256 + kk + (bsw >> 1)
                : Wl + (size_t)(n0 + r) * 256 + kk + ((bsw - 64) >> 1);
            gl_lds16(src, lds + w * 1024);
        }
        #pragma unroll
        for (int t = 0; t < 4; ++t) {   // B: upT rows 128 x 128B = 16KB
            const int q = w * 4096 + t * 1024 + l * 16;
            const int r = q >> 7;
            const int bsw = (q & 127) ^ ((r & 7) << 4);
            const unsigned short* src = (bsw < 64)
                ? upTh + (size_t)(d0 + r) * 256 + kk + (bsw >> 1)
                : upTl + (size_t)(d0 + r) * 256 + kk + ((bsw - 64) >> 1);
            gl_lds16(src, lds + 4096 + w * 4096 + t * 1024);
        }
        __syncthreads();
        const int bq = (l >> 4) * 16;
        f16x8 ah[2], al[2];
        #pragma unroll
        for (int mi = 0; mi < 2; ++mi) {
            const int ra = mi * 16 + (l & 15);
            const int swz = (ra & 7) << 4;
            ah[mi] = *(const f16x8*)(lds + ra * 128 + (bq ^ swz));
            al[mi] = *(const f16x8*)(lds + ra * 128 + ((bq + 64) ^ swz));
        }
        #pragma unroll
        for (int nj = 0; nj < 2; ++nj) {
            const int rb = w * 32 + nj * 16 + (l & 15);
            const int swz = (rb & 7) << 4;
            f16x8 bh = *(const f16x8*)(lds + 4096 + rb * 128 + (bq ^ swz));
            f16x8 bl = *(const f16x8*)(lds + 4096 + rb * 128 + ((bq + 64) ^ swz));
            #pragma unroll
            for (int mi = 0; mi < 2; ++mi) {
                acch[mi][nj] = __builtin_amdgcn_mfma_f32_16x16x32_f16(ah[mi], bh, acch[mi][nj], 0, 0, 0);
                accl[mi][nj] = __builtin_amdgcn_mfma_f32_16x16x32_f16(ah[mi], bl, accl[mi][nj], 0, 0, 0);
                accl[mi][nj] = __builtin_amdgcn_mfma_f32_16x16x32_f16(al[mi], bh, accl[mi][nj], 0, 0, 0);
            }
        }
    }
    #pragma unroll
    for (int mi = 0; mi < 2; ++mi)
        #pragma unroll
        for (int nj = 0; nj < 2; ++nj)
            #pragma unroll
            for (int r = 0; r < 4; ++r) {
                const int row = n0 + mi * 16 + (l >> 4) * 4 + r;
                const int col = d0 + w * 32 + nj * 16 + (l & 15);
                out[(size_t)row * NDIM + col] = fmaf(accl[mi][nj][r], ILSC, acch[mi][nj][r]);
            }
}

extern "C" void kernel_launch(void* const* d_in, const int* in_sizes, int n_in,
                              void* d_out, int out_size, void* d_ws, size_t ws_size,
                              hipStream_t stream) {
    const float* x    = (const float*)d_in[0];
    const float* Wq   = (const float*)d_in[1];
    const float* keys = (const float*)d_in[2];
    const float* down = (const float*)d_in[3];
    const float* up   = (const float*)d_in[4];
    float* out = (float*)d_out;

    char* ws = (char*)d_ws;
    unsigned short* Mth  = (unsigned short*)(ws);                  // 4,456,448 B
    unsigned short* Mtl  = (unsigned short*)(ws + 4456448);        // 4,456,448 B
    unsigned short* xh   = (unsigned short*)(ws + 8912896);        // 2,097,152 B
    unsigned short* xl   = (unsigned short*)(ws + 11010048);       // 2,097,152 B
    unsigned short* Wqh  = (unsigned short*)(ws + 13107200);       // 4,194,304 B
    unsigned short* Wql  = (unsigned short*)(ws + 17301504);       // 4,194,304 B
    unsigned short* ksh  = (unsigned short*)(ws + 21495808);       // 2,097,152 B
    unsigned short* ksl  = (unsigned short*)(ws + 23592960);       // 2,097,152 B
    unsigned short* upTh = (unsigned short*)(ws + 25690112);       //   262,144 B
    unsigned short* upTl = (unsigned short*)(ws + 25952256);       //   262,144 B
    float* T             = (float*)(ws + 26214400);                // 2,097,152 B
    float* D             = (float*)(ws + 30408704);                // 2,097,152 B
    unsigned short* Wh   = (unsigned short*)(ws + 32505856);       // 1,048,576 B
    unsigned short* Wl   = (unsigned short*)(ws + 33554432);       // 1,048,576 B

    kP_split<<<1344, 256, 0, stream>>>(x, Wq, keys, down, up,
                                       xh, xl, Wqh, Wql, ksh, ksl, Mth, Mtl, upTh, upTl);
    kQ_m1<<<dim3(16, 16), 256, 0, stream>>>(Wqh, Wql, ksh, ksl, Mth, Mtl);
    kF_gemm<<<136, 512, 0, stream>>>(xh, xl, Mth, Mtl, T, D);
    kC_combine<<<2048, 256, 0, stream>>>(T, D, Wh, Wl);
    k5_mfma<<<dim3(64, 4), 256, 0, stream>>>(Wh, Wl, upTh, upTl, out);
}

// Round 20
// 94.495 us; speedup vs baseline: 3.8012x; 1.2711x over previous
//
#include <hip/hip_runtime.h>
#include <math.h>

#define N_TOK 2048
#define NDIM 512
#define HEADS 8
#define TOPK 16
#define QCOLS 4096
#define LSC 4096.0f          // scaled-lo (kQ/k5/W paths only)
#define ILSC (1.0f/4096.0f)

typedef __attribute__((ext_vector_type(8))) _Float16 f16x8;
typedef __attribute__((ext_vector_type(4))) float f32x4;

__device__ __forceinline__ unsigned short f32_to_f16(float f) {
    _Float16 h = (_Float16)f;
    return __builtin_bit_cast(unsigned short, h);
}
__device__ __forceinline__ float f16_to_f32(unsigned short u) {
    return (float)__builtin_bit_cast(_Float16, u);
}
__device__ __forceinline__ void gl_lds16(const void* g, void* l) {
    __builtin_amdgcn_global_load_lds(
        (const __attribute__((address_space(1))) void*)g,
        (__attribute__((address_space(3))) void*)l, 16, 0, 0);
}

// ---------------- kP: x -> xc (pre-swizzled staging image, unscaled lo);
// down -> Mc rows 4096..4351; Wq/keys -> fp16 scaled-lo (kQ); up -> upT scaled-lo (k5).
// xc layout: [16 k-steps][2048 rows][128B = hi64|lo64, byte b stored at b^((row&7)<<4)]
// Mc layout: [16 k-steps][4352 mrows][128B same packing]
__device__ __forceinline__ void split_f4s(const float* __restrict__ src,
                                          unsigned short* __restrict__ dh,
                                          unsigned short* __restrict__ dl,
                                          int i, float lsc) {
    float4 v = reinterpret_cast<const float4*>(src)[i];
    float vv[4] = {v.x, v.y, v.z, v.w};
    ushort4 h, lo;
    unsigned short* hp = &h.x; unsigned short* lp = &lo.x;
    #pragma unroll
    for (int q = 0; q < 4; ++q) {
        unsigned short hh = f32_to_f16(vv[q]);
        hp[q] = hh;
        lp[q] = f32_to_f16((vv[q] - f16_to_f32(hh)) * lsc);
    }
    reinterpret_cast<ushort4*>(dh)[i] = h;
    reinterpret_cast<ushort4*>(dl)[i] = lo;
}

__global__ __launch_bounds__(256) void kP_split(const float* __restrict__ x,
                                                const float* __restrict__ Wq,
                                                const float* __restrict__ keys,
                                                const float* __restrict__ down,
                                                const float* __restrict__ up,
                                                char* __restrict__ xc,
                                                unsigned short* __restrict__ Wqh,
                                                unsigned short* __restrict__ Wql,
                                                unsigned short* __restrict__ ksh,
                                                unsigned short* __restrict__ ksl,
                                                char* __restrict__ Mc,
                                                unsigned short* __restrict__ upTh,
                                                unsigned short* __restrict__ upTl) {
    const int bid = blockIdx.x;
    const int tid = threadIdx.x;
    if (bid < 256) {                     // x -> xc (unscaled lo, pre-swizzled)
        #pragma unroll
        for (int t = 0; t < 4; ++t) {
            const int i = bid * 1024 + t * 256 + tid;     // f4 index
            float4 v = reinterpret_cast<const float4*>(x)[i];
            float vv[4] = {v.x, v.y, v.z, v.w};
            ushort4 h, lo;
            unsigned short* hp = &h.x; unsigned short* lp = &lo.x;
            #pragma unroll
            for (int q = 0; q < 4; ++q) {
                unsigned short hh = f32_to_f16(vv[q]);
                hp[q] = hh;
                lp[q] = f32_to_f16(vv[q] - f16_to_f32(hh));
            }
            const int n = i >> 7;                 // token (128 f4 per row)
            const int k0 = (i & 127) * 4;         // k position 0..508
            const int s = k0 >> 5;
            const int o = (k0 & 31) * 2;          // 8B-aligned hi offset
            const int swz = (n & 7) << 4;
            char* base = xc + ((size_t)s * 2048 + n) * 128;
            *reinterpret_cast<ushort4*>(base + (o ^ swz)) = h;
            *reinterpret_cast<ushort4*>(base + ((64 + o) ^ swz)) = lo;
        }
        return;
    }
    if (bid < 768) {                     // Wq: scaled lo
        const int b = bid - 256;
        #pragma unroll
        for (int t = 0; t < 4; ++t) split_f4s(Wq, Wqh, Wql, b * 1024 + t * 256 + tid, LSC);
        return;
    }
    if (bid < 1024) {                    // keys: scaled lo
        const int b = bid - 768;
        #pragma unroll
        for (int t = 0; t < 4; ++t) split_f4s(keys, ksh, ksl, b * 1024 + t * 256 + tid, LSC);
        return;
    }
    if (bid < 1280) {                    // down row e -> Mc mrow 4096+e (unscaled lo)
        const int e = bid - 1024;
        const int d0 = tid * 2;
        float2 v = *reinterpret_cast<const float2*>(&down[(size_t)e * NDIM + d0]);
        ushort2 h, lo;
        unsigned short h0 = f32_to_f16(v.x);
        unsigned short h1 = f32_to_f16(v.y);
        h.x = h0; h.y = h1;
        lo.x = f32_to_f16(v.x - f16_to_f32(h0));
        lo.y = f32_to_f16(v.y - f16_to_f32(h1));
        const int s = d0 >> 5;
        const int o = (d0 & 31) * 2;          // 4B-aligned
        const int mrow = QCOLS + e;
        const int swz = (mrow & 7) << 4;      // == (e&7)<<4
        char* base = Mc + ((size_t)s * 4352 + mrow) * 128;
        *reinterpret_cast<ushort2*>(base + (o ^ swz)) = h;
        *reinterpret_cast<ushort2*>(base + ((64 + o) ^ swz)) = lo;
        return;
    }
    // upT: scaled lo (k5 path)
    const int b = bid - 1280;
    #pragma unroll
    for (int dd = 0; dd < 8; ++dd) {
        const int d = b * 8 + dd;
        const int e = tid;
        const float v = up[(size_t)e * NDIM + d];
        unsigned short hh = f32_to_f16(v);
        upTh[(size_t)d * 256 + e] = hh;
        upTl[(size_t)d * 256 + e] = f32_to_f16((v - f16_to_f32(hh)) * LSC);
    }
}

// ---------------- kQ: M = Wq_slice @ keys^T (scaled-lo dual-acc), epilogue writes
// Mc staging image (unscaled lo, pre-swizzled). grid (16,16).
__global__ __launch_bounds__(256) void kQ_m1(const unsigned short* __restrict__ Wqh,
                                             const unsigned short* __restrict__ Wql,
                                             const unsigned short* __restrict__ ksh,
                                             const unsigned short* __restrict__ ksl,
                                             char* __restrict__ Mc) {
    __shared__ __align__(16) char lds[36864];   // A 4KB + B 32KB
    const int tid = threadIdx.x;
    const int w = tid >> 6, l = tid & 63;
    const int c0 = blockIdx.x * 32;
    const int ph = blockIdx.y;
    const int p = ph >> 3, h = ph & 7;
    const int off = p * 2048 + h * 256;
    f32x4 acch[2][4] = {};
    f32x4 accl[2][4] = {};

    for (int s = 0; s < 8; ++s) {
        const int kk = s * 32;
        __syncthreads();
        {   // A: 32 rows x 128B = 4KB
            const int q = w * 1024 + l * 16;
            const int r = q >> 7;
            const int bsw = (q & 127) ^ ((r & 7) << 4);
            const unsigned short* src = (bsw < 64)
                ? Wqh + (size_t)(c0 + r) * QCOLS + off + kk + (bsw >> 1)
                : Wql + (size_t)(c0 + r) * QCOLS + off + kk + ((bsw - 64) >> 1);
            gl_lds16(src, lds + w * 1024);
        }
        #pragma unroll
        for (int t = 0; t < 8; ++t) {   // B: 256 rows x 128B = 32KB
            const int q = w * 8192 + t * 1024 + l * 16;
            const int r = q >> 7;
            const int bsw = (q & 127) ^ ((r & 7) << 4);
            const unsigned short* src = (bsw < 64)
                ? ksh + ((size_t)(h * 256 + r) * 2 + p) * 256 + kk + (bsw >> 1)
                : ksl + ((size_t)(h * 256 + r) * 2 + p) * 256 + kk + ((bsw - 64) >> 1);
            gl_lds16(src, lds + 4096 + w * 8192 + t * 1024);
        }
        __syncthreads();
        const int bq = (l >> 4) * 16;
        f16x8 ah[2], al[2];
        #pragma unroll
        for (int mi = 0; mi < 2; ++mi) {
            const int ra = mi * 16 + (l & 15);
            const int swz = (ra & 7) << 4;
            ah[mi] = *(const f16x8*)(lds + ra * 128 + (bq ^ swz));
            al[mi] = *(const f16x8*)(lds + ra * 128 + ((bq + 64) ^ swz));
        }
        __builtin_amdgcn_s_setprio(1);
        #pragma unroll
        for (int nj = 0; nj < 4; ++nj) {
            const int rb = w * 64 + nj * 16 + (l & 15);
            const int swz = (rb & 7) << 4;
            f16x8 bh = *(const f16x8*)(lds + 4096 + rb * 128 + (bq ^ swz));
            f16x8 bl = *(const f16x8*)(lds + 4096 + rb * 128 + ((bq + 64) ^ swz));
            #pragma unroll
            for (int mi = 0; mi < 2; ++mi) {
                acch[mi][nj] = __builtin_amdgcn_mfma_f32_16x16x32_f16(ah[mi], bh, acch[mi][nj], 0, 0, 0);
                accl[mi][nj] = __builtin_amdgcn_mfma_f32_16x16x32_f16(ah[mi], bl, accl[mi][nj], 0, 0, 0);
                accl[mi][nj] = __builtin_amdgcn_mfma_f32_16x16x32_f16(al[mi], bh, accl[mi][nj], 0, 0, 0);
            }
        }
        __builtin_amdgcn_s_setprio(0);
    }
    #pragma unroll
    for (int mi = 0; mi < 2; ++mi)
        #pragma unroll
        for (int nj = 0; nj < 4; ++nj) {
            const int k = w * 64 + nj * 16 + (l & 15);
            const int cb = c0 + mi * 16 + (l >> 4) * 4;      // K-dim position
            ushort4 h4, l4;
            unsigned short* hp = &h4.x; unsigned short* lp = &l4.x;
            #pragma unroll
            for (int r = 0; r < 4; ++r) {
                const float v = fmaf(accl[mi][nj][r], ILSC, acch[mi][nj][r]);
                unsigned short hh = f32_to_f16(v);
                hp[r] = hh;
                lp[r] = f32_to_f16(v - f16_to_f32(hh));   // unscaled lo for kF
            }
            const int mrow = off + k;
            const int s2 = cb >> 5;
            const int o = (cb & 31) * 2;                  // 8B-aligned
            const int swz2 = (mrow & 7) << 4;
            char* base = Mc + ((size_t)s2 * 4352 + mrow) * 128;
            *reinterpret_cast<ushort4*>(base + (o ^ swz2)) = h4;
            *reinterpret_cast<ushort4*>(base + ((64 + o) ^ swz2)) = l4;
        }
}

// ---------------- kF: fused sim GEMM + phase-1 half-group top-16.
// BM=BN=128, BK=32, dbuf, 2x2 wave tiles, XCD swizzle. Staging = PURE LINEAR
// copy from pre-swizzled xc/Mc (single buffer, coalesced, no per-lane addressing).
#define BM 128
#define BN 128
#define BK 32
#define KFBUF 32768
__global__ __launch_bounds__(256, 2) void kF_gemm(const char* __restrict__ xc,
                                                  const char* __restrict__ Mc,
                                                  float* __restrict__ T,
                                                  float* __restrict__ D) {
    __shared__ __align__(16) char lds[2 * KFBUF];   // 64 KB
    const int tid = threadIdx.x;
    const int w = tid >> 6, l = tid & 63;
    const int wm = w >> 1, wn = w & 1;              // 2x2 wave grid, 64x64 tiles
    const int orig = blockIdx.x;                    // 0..543
    const int swz = (orig & 7) * 68 + (orig >> 3);  // bijective XCD swizzle
    const int by = swz >> 4;                        // 0..33 (col strip)
    const int row0 = (swz & 15) * BM;
    const int colbase = by * 128;
    f32x4 acc[4][4] = {};

    auto stage = [&](int buf, int s) {
        char* base = lds + buf * KFBUF;
        const char* asrc = xc + ((size_t)s * 2048 + row0) * 128;
        const char* bsrc = Mc + ((size_t)s * 4352 + colbase) * 128;
        #pragma unroll
        for (int t = 0; t < 4; ++t) {               // A,B: 16KB each, linear
            gl_lds16(asrc + t * 4096 + tid * 16, base + t * 4096 + tid * 16);
            gl_lds16(bsrc + t * 4096 + tid * 16, base + 16384 + t * 4096 + tid * 16);
        }
    };

    stage(0, 0);
    __syncthreads();
    for (int s = 0; s < 16; ++s) {
        if (s + 1 < 16) stage((s + 1) & 1, s + 1);
        const char* base = lds + (s & 1) * KFBUF;
        const int bq = (l >> 4) * 16;
        f16x8 bh[4], bl[4];
        #pragma unroll
        for (int nj = 0; nj < 4; ++nj) {
            const int rb = wn * 64 + nj * 16 + (l & 15);
            const int sz = (rb & 7) << 4;
            bh[nj] = *(const f16x8*)(base + 16384 + rb * 128 + (bq ^ sz));
            bl[nj] = *(const f16x8*)(base + 16384 + rb * 128 + ((bq + 64) ^ sz));
        }
        __builtin_amdgcn_s_setprio(1);
        #pragma unroll
        for (int mi = 0; mi < 4; ++mi) {
            const int ra = wm * 64 + mi * 16 + (l & 15);
            const int sz = (ra & 7) << 4;
            f16x8 ah = *(const f16x8*)(base + ra * 128 + (bq ^ sz));
            f16x8 al = *(const f16x8*)(base + ra * 128 + ((bq + 64) ^ sz));
            #pragma unroll
            for (int nj = 0; nj < 4; ++nj) {
                acc[mi][nj] = __builtin_amdgcn_mfma_f32_16x16x32_f16(ah, bh[nj], acc[mi][nj], 0, 0, 0);
                acc[mi][nj] = __builtin_amdgcn_mfma_f32_16x16x32_f16(ah, bl[nj], acc[mi][nj], 0, 0, 0);
                acc[mi][nj] = __builtin_amdgcn_mfma_f32_16x16x32_f16(al, bh[nj], acc[mi][nj], 0, 0, 0);
            }
        }
        __builtin_amdgcn_s_setprio(0);
        __syncthreads();
    }

    if (by >= 32) {     // D half-block: direct store
        #pragma unroll
        for (int mi = 0; mi < 4; ++mi)
            #pragma unroll
            for (int nj = 0; nj < 4; ++nj)
                #pragma unroll
                for (int r = 0; r < 4; ++r) {
                    const int row = row0 + wm * 64 + mi * 16 + (l >> 4) * 4 + r;
                    const int col = (by - 32) * 128 + wn * 64 + nj * 16 + (l & 15);
                    D[(size_t)row * 256 + col] = acc[mi][nj][r];
                }
        return;
    }

    // epilogue: 4 chunks of 32 rows; Cl[32][136]; 8-lane-group sorts (UNROLLED).
    float* Cl = (float*)lds;
    const int grp8 = tid >> 3;
    const int lam8 = tid & 7;
    #pragma unroll
    for (int c = 0; c < 4; ++c) {
        if (wm == (c >> 1)) {
            #pragma unroll
            for (int u = 0; u < 2; ++u) {
                const int mi = (c & 1) * 2 + u;
                #pragma unroll
                for (int nj = 0; nj < 4; ++nj)
                    #pragma unroll
                    for (int r = 0; r < 4; ++r)
                        Cl[(u * 16 + (l >> 4) * 4 + r) * 136 + wn * 64 + nj * 16 + (l & 15)] =
                            acc[mi][nj][r];
            }
        }
        __syncthreads();
        {
            float v[16];
            #pragma unroll
            for (int j = 0; j < 16; ++j) v[j] = Cl[grp8 * 136 + lam8 + 8 * j];
            #pragma unroll
            for (int k = 2; k <= 16; k <<= 1)
                #pragma unroll
                for (int j = k >> 1; j > 0; j >>= 1)
                    #pragma unroll
                    for (int i = 0; i < 16; ++i) {
                        const int l2 = i ^ j;
                        if (l2 > i) {
                            const bool asc = ((i & k) == 0);
                            const float lo = fminf(v[i], v[l2]), hi = fmaxf(v[i], v[l2]);
                            v[i] = asc ? lo : hi;
                            v[l2] = asc ? hi : lo;
                        }
                    }
            #pragma unroll
            for (int lvl = 1; lvl <= 4; lvl <<= 1) {
                float m[16];
                #pragma unroll
                for (int q = 0; q < 16; ++q)
                    m[q] = fmaxf(v[q], __shfl_xor(v[15 - q], lvl));
                #pragma unroll
                for (int j = 8; j > 0; j >>= 1)
                    #pragma unroll
                    for (int i = 0; i < 16; ++i) {
                        const int l2 = i ^ j;
                        if (l2 > i) {
                            const float lo = fminf(m[i], m[l2]), hi = fmaxf(m[i], m[l2]);
                            m[i] = lo; m[l2] = hi;
                        }
                    }
                #pragma unroll
                for (int q = 0; q < 16; ++q) v[q] = m[q];
            }
            const int n = row0 + c * 32 + grp8;
            T[((size_t)n * 32 + by) * 16 + 2 * lam8]     = v[15 - 2 * lam8];
            T[((size_t)n * 32 + by) * 16 + 2 * lam8 + 1] = v[14 - 2 * lam8];
        }
        __syncthreads();
    }
}

// ---------------- kC: merge half-lists -> 50 candidates -> top-16 -> softmax*gelu(D)
__device__ const unsigned short CAND_TBL[32] = {
    0x0100, 0x0302, 0x0504, 0x0706, 0x0908, 0x0B0A, 0x0D0C, 0x0F0E,
    0x1110, 0x1312, 0x1514, 0x1716,
    0x2120, 0x2322, 0x3024, 0x3231, 0x4033, 0x4241,
    0x5150, 0x6160, 0x7170,
    0x9080, 0xB0A0, 0xD0C0, 0xF0E0,
    0xFFFF, 0xFFFF, 0xFFFF, 0xFFFF, 0xFFFF, 0xFFFF, 0xFFFF
};

__device__ __forceinline__ float sel16(const float a[16], int i) {
    float b0 = (i & 1) ? a[1] : a[0];
    float b1 = (i & 1) ? a[3] : a[2];
    float b2 = (i & 1) ? a[5] : a[4];
    float b3 = (i & 1) ? a[7] : a[6];
    float b4 = (i & 1) ? a[9] : a[8];
    float b5 = (i & 1) ? a[11] : a[10];
    float b6 = (i & 1) ? a[13] : a[12];
    float b7 = (i & 1) ? a[15] : a[14];
    float c0 = (i & 2) ? b1 : b0;
    float c1 = (i & 2) ? b3 : b2;
    float c2 = (i & 2) ? b5 : b4;
    float c3 = (i & 2) ? b7 : b6;
    float d0 = (i & 4) ? c1 : c0;
    float d1 = (i & 4) ? c3 : c2;
    return (i & 8) ? d1 : d0;
}

__device__ __forceinline__ void merge_desc16(const float* __restrict__ a,
                                             const float* __restrict__ b,
                                             float out_desc[16]) {
    float m[16];
    #pragma unroll
    for (int q = 0; q < 16; ++q) m[q] = fmaxf(a[q], b[15 - q]);
    #pragma unroll
    for (int k = 2; k <= 16; k <<= 1)
        #pragma unroll
        for (int j = k >> 1; j > 0; j >>= 1)
            #pragma unroll
            for (int i = 0; i < 16; ++i) {
                const int l2 = i ^ j;
                if (l2 > i) {
                    const bool asc = ((i & k) == 0);
                    const float lo = fminf(m[i], m[l2]), hi = fmaxf(m[i], m[l2]);
                    m[i] = asc ? lo : hi;
                    m[l2] = asc ? hi : lo;
                }
            }
    #pragma unroll
    for (int q = 0; q < 16; ++q) out_desc[q] = m[15 - q];
}

__global__ __launch_bounds__(256) void kC_combine(const float* __restrict__ T,
                                                  const float* __restrict__ D,
                                                  unsigned short* __restrict__ Wh,
                                                  unsigned short* __restrict__ Wl) {
    __shared__ unsigned long long ckey[8][50];
    __shared__ float winval[8][16];
    __shared__ int winflat[8][16];
    __shared__ int Wrow[256];

    const int tid = threadIdx.x;
    const int n = blockIdx.x;
    const int h = tid >> 5;
    const int lam = tid & 15;

    Wrow[tid] = 0;

    float a0[16], a1[16], b0v[16], b1v[16];
    const float* t00 = &T[((size_t)n * 32 + 2 * h) * 16];
    const float* t01 = &T[((size_t)n * 32 + 2 * h + 1) * 16];
    const float* t10 = &T[((size_t)n * 32 + 16 + 2 * h) * 16];
    const float* t11 = &T[((size_t)n * 32 + 17 + 2 * h) * 16];
    #pragma unroll
    for (int q = 0; q < 16; ++q) {
        a0[q] = t00[q]; a1[q] = t01[q];
        b0v[q] = t10[q]; b1v[q] = t11[q];
    }
    float sxd[16], syd[16];
    merge_desc16(a0, a1, sxd);
    merge_desc16(b0v, b1v, syd);

    const int lc = tid & 31;
    const unsigned int cw = CAND_TBL[lc];
    unsigned long long mykey[2]; float myval[2]; int myflat[2]; int myrank[2] = {0, 0};
    #pragma unroll
    for (int u = 0; u < 2; ++u) {
        const int fl = (cw >> (8 * u)) & 0xFF;
        const float sv = sel16(sxd, fl >> 4) + sel16(syd, fl & 15);
        const unsigned int uv = __float_as_uint(sv);
        const unsigned int mo = (uv & 0x80000000u) ? ~uv : (uv | 0x80000000u);
        mykey[u] = ((unsigned long long)mo << 8) | (unsigned long long)(255 - fl);
        myval[u] = sv; myflat[u] = fl;
        const int slot = lc * 2 + u;
        if (slot < 50) ckey[h][slot] = mykey[u];
    }
    __syncthreads();
    for (int kk = 0; kk < 50; ++kk) {
        const unsigned long long ok = ckey[h][kk];
        myrank[0] += (ok > mykey[0]) ? 1 : 0;
        myrank[1] += (ok > mykey[1]) ? 1 : 0;
    }
    #pragma unroll
    for (int u = 0; u < 2; ++u)
        if (myrank[u] < 16) { winval[h][myrank[u]] = myval[u]; winflat[h][myrank[u]] = myflat[u]; }
    __syncthreads();

    if (!(tid & 16)) {
        const float sc = winval[h][lam];
        const float m0 = winval[h][0];
        float e = expf(sc - m0);
        float esum = e;
        #pragma unroll
        for (int off = 1; off < 16; off <<= 1) esum += __shfl_xor(esum, off);
        const int fl = winflat[h][lam];
        const float hv = D[(size_t)n * 256 + fl];
        const float gg = 0.5f * hv * (1.0f + erff(hv * 0.70710678118654752f));
        const float wv = (e / esum) * gg;
        atomicAdd(&Wrow[fl], __float2int_rn(wv * 4194304.0f));
    }
    __syncthreads();
    const float wfin = (float)Wrow[tid] * (1.0f / 4194304.0f);
    const unsigned short hh = f32_to_f16(wfin);
    Wh[(size_t)n * 256 + tid] = hh;
    Wl[(size_t)n * 256 + tid] = f32_to_f16((wfin - f16_to_f32(hh)) * LSC);
}

// ---------------- k5: out = W @ up256, scaled-lo dual-acc
__global__ __launch_bounds__(256) void k5_mfma(const unsigned short* __restrict__ Wh,
                                               const unsigned short* __restrict__ Wl,
                                               const unsigned short* __restrict__ upTh,
                                               const unsigned short* __restrict__ upTl,
                                               float* __restrict__ out) {
    __shared__ __align__(16) char lds[20480];   // A 4KB + B 16KB
    const int tid = threadIdx.x;
    const int w = tid >> 6, l = tid & 63;
    const int n0 = blockIdx.x * 32;
    const int d0 = blockIdx.y * 128;
    f32x4 acch[2][2] = {};
    f32x4 accl[2][2] = {};

    for (int s = 0; s < 8; ++s) {
        const int kk = s * 32;
        __syncthreads();
        {   // A: W rows 32 x 128B = 4KB
            const int q = w * 1024 + l * 16;
            const int r = q >> 7;
            const int bsw = (q & 127) ^ ((r & 7) << 4);
            const unsigned short* src = (bsw < 64)
                ? Wh + (size_t)(n0 + r) * 256 + kk + (bsw >> 1)
                : Wl + (size_t)(n0 + r) * 256 + kk + ((bsw - 64) >> 1);
            gl_lds16(src, lds + w * 1024);
        }
        #pragma unroll
        for (int t = 0; t < 4; ++t) {   // B: upT rows 128 x 128B = 16KB
            const int q = w * 4096 + t * 1024 + l * 16;
            const int r = q >> 7;
            const int bsw = (q & 127) ^ ((r & 7) << 4);
            const unsigned short* src = (bsw < 64)
                ? upTh + (size_t)(d0 + r) * 256 + kk + (bsw >> 1)
                : upTl + (size_t)(d0 + r) * 256 + kk + ((bsw - 64) >> 1);
            gl_lds16(src, lds + 4096 + w * 4096 + t * 1024);
        }
        __syncthreads();
        const int bq = (l >> 4) * 16;
        f16x8 ah[2], al[2];
        #pragma unroll
        for (int mi = 0; mi < 2; ++mi) {
            const int ra = mi * 16 + (l & 15);
            const int swz = (ra & 7) << 4;
            ah[mi] = *(const f16x8*)(lds + ra * 128 + (bq ^ swz));
            al[mi] = *(const f16x8*)(lds + ra * 128 + ((bq + 64) ^ swz));
        }
        #pragma unroll
        for (int nj = 0; nj < 2; ++nj) {
            const int rb = w * 32 + nj * 16 + (l & 15);
            const int swz = (rb & 7) << 4;
            f16x8 bh = *(const f16x8*)(lds + 4096 + rb * 128 + (bq ^ swz));
            f16x8 bl = *(const f16x8*)(lds + 4096 + rb * 128 + ((bq + 64) ^ swz));
            #pragma unroll
            for (int mi = 0; mi < 2; ++mi) {
                acch[mi][nj] = __builtin_amdgcn_mfma_f32_16x16x32_f16(ah[mi], bh, acch[mi][nj], 0, 0, 0);
                accl[mi][nj] = __builtin_amdgcn_mfma_f32_16x16x32_f16(ah[mi], bl, accl[mi][nj], 0, 0, 0);
                accl[mi][nj] = __builtin_amdgcn_mfma_f32_16x16x32_f16(al[mi], bh, accl[mi][nj], 0, 0, 0);
            }
        }
    }
    #pragma unroll
    for (int mi = 0; mi < 2; ++mi)
        #pragma unroll
        for (int nj = 0; nj < 2; ++nj)
            #pragma unroll
            for (int r = 0; r < 4; ++r) {
                const int row = n0 + mi * 16 + (l >> 4) * 4 + r;
                const int col = d0 + w * 32 + nj * 16 + (l & 15);
                out[(size_t)row * NDIM + col] = fmaf(accl[mi][nj][r], ILSC, acch[mi][nj][r]);
            }
}

extern "C" void kernel_launch(void* const* d_in, const int* in_sizes, int n_in,
                              void* d_out, int out_size, void* d_ws, size_t ws_size,
                              hipStream_t stream) {
    const float* x    = (const float*)d_in[0];
    const float* Wq   = (const float*)d_in[1];
    const float* keys = (const float*)d_in[2];
    const float* down = (const float*)d_in[3];
    const float* up   = (const float*)d_in[4];
    float* out = (float*)d_out;

    char* ws = (char*)d_ws;
    char* Mc             = ws;                                     // 16*4352*128 = 8,912,896 B
    char* xc             = ws + 8912896;                           // 16*2048*128 = 4,194,304 B
    unsigned short* Wqh  = (unsigned short*)(ws + 13107200);       // 4,194,304 B
    unsigned short* Wql  = (unsigned short*)(ws + 17301504);       // 4,194,304 B
    unsigned short* ksh  = (unsigned short*)(ws + 21495808);       // 2,097,152 B
    unsigned short* ksl  = (unsigned short*)(ws + 23592960);       // 2,097,152 B
    unsigned short* upTh = (unsigned short*)(ws + 25690112);       //   262,144 B
    unsigned short* upTl = (unsigned short*)(ws + 25952256);       //   262,144 B
    float* T             = (float*)(ws + 26214400);                // 4,194,304 B (2048*32*16)
    float* D             = (float*)(ws + 30408704);                // 2,097,152 B
    unsigned short* Wh   = (unsigned short*)(ws + 32505856);       // 1,048,576 B
    unsigned short* Wl   = (unsigned short*)(ws + 33554432);       // 1,048,576 B

    kP_split<<<1344, 256, 0, stream>>>(x, Wq, keys, down, up,
                                       xc, Wqh, Wql, ksh, ksl, Mc, upTh, upTl);
    kQ_m1<<<dim3(16, 16), 256, 0, stream>>>(Wqh, Wql, ksh, ksl, Mc);
    kF_gemm<<<544, 256, 0, stream>>>(xc, Mc, T, D);
    kC_combine<<<2048, 256, 0, stream>>>(T, D, Wh, Wl);
    k5_mfma<<<dim3(64, 4), 256, 0, stream>>>(Wh, Wl, upTh, upTl, out);
}